// Round 1
// baseline (199.008 us; speedup 1.0000x reference)
//
#include <hip/hip_runtime.h>

#define DD 256
#define BB 8
#define NA 360
#define CH 4            // h-chunks per angle
#define HC (DD / CH)    // 64 h-steps per chunk

// Pack x (B,1,D,D) into batch-innermost layouts:
//   pN[(y*D+x)*B + b]  (normal)
//   pT[(x*D+y)*B + b]  (transposed)
__global__ __launch_bounds__(256) void pack_kernel(const float* __restrict__ x,
                                                   float* __restrict__ pN,
                                                   float* __restrict__ pT) {
    int idx = blockIdx.x * 256 + threadIdx.x;   // 0..65535
    int y = idx >> 8;
    int xx = idx & 255;
    float v[BB];
#pragma unroll
    for (int b = 0; b < BB; ++b) v[b] = x[b * DD * DD + idx];
#pragma unroll
    for (int b = 0; b < BB; ++b) pN[idx * BB + b] = v[b];
#pragma unroll
    for (int b = 0; b < BB; ++b) pT[(xx * DD + y) * BB + b] = v[b];
}

struct F8 { float4 lo, hi; };

__device__ __forceinline__ void acc8(float* acc, const F8& q, float wgt) {
    acc[0] = fmaf(q.lo.x, wgt, acc[0]);
    acc[1] = fmaf(q.lo.y, wgt, acc[1]);
    acc[2] = fmaf(q.lo.z, wgt, acc[2]);
    acc[3] = fmaf(q.lo.w, wgt, acc[3]);
    acc[4] = fmaf(q.hi.x, wgt, acc[4]);
    acc[5] = fmaf(q.hi.y, wgt, acc[5]);
    acc[6] = fmaf(q.hi.z, wgt, acc[6]);
    acc[7] = fmaf(q.hi.w, wgt, acc[7]);
}

__global__ __launch_bounds__(256) void radon_kernel(const float* __restrict__ pN,
                                                    const float* __restrict__ pT,
                                                    float* __restrict__ out) {
    const int a  = blockIdx.x;   // angle
    const int hc = blockIdx.y;   // h-chunk
    const int w  = threadIdx.x;  // output column

    // angle = a*0.5 deg (exact in fp32); t = deg2rad(angle) in fp32 like ref
    float ang = (float)a * 0.5f;
    float t = ang * 0.017453292519943295f;
    float s = sinf(t);
    float c = cosf(t);

    // ix = c*uw - s*uh + 127.5 ; iy = s*uw + c*uh + 127.5 ; u(k)=k-127.5
    float uw  = (float)w - 127.5f;
    float axN = fmaf(c, uw, 127.5f);
    float ayN = fmaf(s, uw, 127.5f);

    // Pick layout so consecutive "inner" coordinate is memory-contiguous:
    // spread across lanes ~ min(|s|,|c|)*D instead of |s|*D.
    const float* __restrict__ P;
    float ax, dx, ay, dy;   // inner coord = ax + dx*uh ; outer (row) = ay + dy*uh
    if (fabsf(s) <= fabsf(c)) { P = pN; ax = axN; dx = -s; ay = ayN; dy = c;  }
    else                      { P = pT; ax = ayN; dx = c;  ay = axN; dy = -s; }

    float acc[BB];
#pragma unroll
    for (int b = 0; b < BB; ++b) acc[b] = 0.f;

    const int h0 = hc * HC;
    for (int i = 0; i < HC; ++i) {
        float uh = (float)(h0 + i) - 127.5f;
        float ix = fmaf(dx, uh, ax);   // inner (contiguous) coord
        float iy = fmaf(dy, uh, ay);   // outer (row) coord
        float x0f = floorf(ix), y0f = floorf(iy);
        float wx1 = ix - x0f, wy1 = iy - y0f;
        float wx0 = 1.f - wx1, wy0 = 1.f - wy1;
        int x0 = (int)x0f, y0 = (int)y0f;
        // per-corner validity (matches ref: weight zeroed when outside [0,255])
        float vx0 = ((unsigned)x0 < 256u) ? wx0 : 0.f;
        float vx1 = ((unsigned)(x0 + 1) < 256u) ? wx1 : 0.f;
        float vy0 = ((unsigned)y0 < 256u) ? wy0 : 0.f;
        float vy1 = ((unsigned)(y0 + 1) < 256u) ? wy1 : 0.f;
        int x0c = min(max(x0, 0), 255);
        int x1c = min(max(x0 + 1, 0), 255);
        int y0c = min(max(y0, 0), 255);
        int y1c = min(max(y0 + 1, 0), 255);
        float w00 = vx0 * vy0, w10 = vx1 * vy0;
        float w01 = vx0 * vy1, w11 = vx1 * vy1;

        const float4* p00 = (const float4*)(P + (y0c * DD + x0c) * BB);
        const float4* p10 = (const float4*)(P + (y0c * DD + x1c) * BB);
        const float4* p01 = (const float4*)(P + (y1c * DD + x0c) * BB);
        const float4* p11 = (const float4*)(P + (y1c * DD + x1c) * BB);
        F8 q00, q10, q01, q11;
        q00.lo = p00[0]; q00.hi = p00[1];
        q10.lo = p10[0]; q10.hi = p10[1];
        q01.lo = p01[0]; q01.hi = p01[1];
        q11.lo = p11[0]; q11.hi = p11[1];

        acc8(acc, q00, w00);
        acc8(acc, q10, w10);
        acc8(acc, q01, w01);
        acc8(acc, q11, w11);
    }

    const float sc = 1.0f / 256.0f;
    float* o = out + (size_t)a * DD + w;
#pragma unroll
    for (int b = 0; b < BB; ++b)
        atomicAdd(o + (size_t)b * NA * DD, acc[b] * sc);
}

// Fallback if workspace is too small for packed copies: gather directly
// from the original (B,D,D) layout, 4 dword loads per corner per batch.
__global__ __launch_bounds__(256) void radon_direct(const float* __restrict__ x,
                                                    float* __restrict__ out) {
    const int a  = blockIdx.x;
    const int hc = blockIdx.y;
    const int w  = threadIdx.x;
    float ang = (float)a * 0.5f;
    float t = ang * 0.017453292519943295f;
    float s = sinf(t);
    float c = cosf(t);
    float uw = (float)w - 127.5f;
    float ax = fmaf(c, uw, 127.5f);
    float ay = fmaf(s, uw, 127.5f);

    float acc[BB];
#pragma unroll
    for (int b = 0; b < BB; ++b) acc[b] = 0.f;

    const int h0 = hc * HC;
    for (int i = 0; i < HC; ++i) {
        float uh = (float)(h0 + i) - 127.5f;
        float ix = fmaf(-s, uh, ax);
        float iy = fmaf(c, uh, ay);
        float x0f = floorf(ix), y0f = floorf(iy);
        float wx1 = ix - x0f, wy1 = iy - y0f;
        float wx0 = 1.f - wx1, wy0 = 1.f - wy1;
        int x0 = (int)x0f, y0 = (int)y0f;
        float vx0 = ((unsigned)x0 < 256u) ? wx0 : 0.f;
        float vx1 = ((unsigned)(x0 + 1) < 256u) ? wx1 : 0.f;
        float vy0 = ((unsigned)y0 < 256u) ? wy0 : 0.f;
        float vy1 = ((unsigned)(y0 + 1) < 256u) ? wy1 : 0.f;
        int x0c = min(max(x0, 0), 255);
        int x1c = min(max(x0 + 1, 0), 255);
        int y0c = min(max(y0, 0), 255);
        int y1c = min(max(y0 + 1, 0), 255);
        float w00 = vx0 * vy0, w10 = vx1 * vy0;
        float w01 = vx0 * vy1, w11 = vx1 * vy1;
        int l00 = y0c * DD + x0c, l10 = y0c * DD + x1c;
        int l01 = y1c * DD + x0c, l11 = y1c * DD + x1c;
#pragma unroll
        for (int b = 0; b < BB; ++b) {
            const float* ib = x + (size_t)b * DD * DD;
            acc[b] = fmaf(ib[l00], w00, acc[b]);
            acc[b] = fmaf(ib[l10], w10, acc[b]);
            acc[b] = fmaf(ib[l01], w01, acc[b]);
            acc[b] = fmaf(ib[l11], w11, acc[b]);
        }
    }

    const float sc = 1.0f / 256.0f;
    float* o = out + (size_t)a * DD + w;
#pragma unroll
    for (int b = 0; b < BB; ++b)
        atomicAdd(o + (size_t)b * NA * DD, acc[b] * sc);
}

extern "C" void kernel_launch(void* const* d_in, const int* in_sizes, int n_in,
                              void* d_out, int out_size, void* d_ws, size_t ws_size,
                              hipStream_t stream) {
    const float* x = (const float*)d_in[0];
    float* out = (float*)d_out;

    // out is poisoned 0xAA each call; we accumulate with atomics -> zero it.
    hipMemsetAsync(d_out, 0, (size_t)out_size * sizeof(float), stream);

    const size_t need = 2ull * DD * DD * BB * sizeof(float);  // 4 MiB
    if (ws_size >= need) {
        float* pN = (float*)d_ws;
        float* pT = pN + (size_t)DD * DD * BB;
        pack_kernel<<<DD * DD / 256, 256, 0, stream>>>(x, pN, pT);
        radon_kernel<<<dim3(NA, CH), 256, 0, stream>>>(pN, pT, out);
    } else {
        radon_direct<<<dim3(NA, CH), 256, 0, stream>>>(x, out);
    }
}